// Round 1
// baseline (494.325 us; speedup 1.0000x reference)
//
#include <hip/hip_runtime.h>
#include <cstdint>
#include <cstddef>

// ---------------------------------------------------------------------------
// BNN pipeline:
//  L1: conv7x7(sign(x), sign(w1)) -> BN(train) -> leaky(0.5)
//  L2: conv1x1(sign(.), sign(w2)) -> BN(train) -> leaky(0.5)
//  L3: conv5x5 fp32 (64->1)
// Shapes: x (16,1,256,256), out (16,1,256,256)
// ---------------------------------------------------------------------------

#define NPIX_PER_CH (16.0 * 256.0 * 256.0)   // elements per channel for BN

// ---- workspace layout helpers ----------------------------------------------
// h2s   : int8  [16][64][256][256]  (stores h2/2, values in [-64,64])  67,108,864 B
// xbits : u64   [16][256][6]                                             196,608 B
// wb1   : u64   [128]
// w2lo  : u64   [64]
// w2hi  : u64   [64]
// st1   : i64   [256]  (sum[128], sumsq[128])
// st2   : i64   [128]  (sum[64],  sumsq[64])
// a1,c1 : f32   [128] each
// a2,c2 : f32   [64] each

struct WS {
    int8_t*   h2s;
    uint64_t* xbits;
    uint64_t* wb1;
    uint64_t* w2lo;
    uint64_t* w2hi;
    long long* st1;
    long long* st2;
    float* a1; float* c1;
    float* a2; float* c2;
};

static inline WS carve(void* d_ws) {
    WS w;
    uint8_t* p = (uint8_t*)d_ws;
    w.h2s   = (int8_t*)p;              p += (size_t)16 * 64 * 256 * 256;
    w.xbits = (uint64_t*)p;            p += (size_t)16 * 256 * 6 * 8;
    w.wb1   = (uint64_t*)p;            p += 128 * 8;
    w.w2lo  = (uint64_t*)p;            p += 64 * 8;
    w.w2hi  = (uint64_t*)p;            p += 64 * 8;
    w.st1   = (long long*)p;           p += 256 * 8;
    w.st2   = (long long*)p;           p += 128 * 8;
    w.a1    = (float*)p;               p += 128 * 4;
    w.c1    = (float*)p;               p += 128 * 4;
    w.a2    = (float*)p;               p += 64 * 4;
    w.c2    = (float*)p;               p += 64 * 4;
    return w;
}

// ---- K0: pack sign bits of x into padded per-row words ---------------------
// word j of a row covers bitpos = x+8 in [64j, 64j+63]; 6 words/row (last 0).
// bit = 1  <=>  x < 0  (i.e. binarized value is -1)
__global__ __launch_bounds__(256) void k_pack_x(const float* __restrict__ x,
                                                uint64_t* __restrict__ xbits) {
    int rowId = blockIdx.x * 4 + (threadIdx.x >> 6);   // 0..4095  (n*256+y)
    int lane  = threadIdx.x & 63;
    const float* row = x + (size_t)rowId * 256;
    uint64_t b0 = __ballot(row[0 * 64 + lane] < 0.0f);
    uint64_t b1 = __ballot(row[1 * 64 + lane] < 0.0f);
    uint64_t b2 = __ballot(row[2 * 64 + lane] < 0.0f);
    uint64_t b3 = __ballot(row[3 * 64 + lane] < 0.0f);
    if (lane == 0) {
        uint64_t* o = xbits + (size_t)rowId * 6;
        o[0] = b0 << 8;
        o[1] = (b0 >> 56) | (b1 << 8);
        o[2] = (b1 >> 56) | (b2 << 8);
        o[3] = (b2 >> 56) | (b3 << 8);
        o[4] = b3 >> 56;
        o[5] = 0;
    }
}

// ---- K1: pack weight sign bits, zero stat accumulators ---------------------
__global__ void k_pack_w(const float* __restrict__ w1, const float* __restrict__ w2,
                         uint64_t* __restrict__ wb1, uint64_t* __restrict__ w2lo,
                         uint64_t* __restrict__ w2hi,
                         long long* __restrict__ st1, long long* __restrict__ st2) {
    int t = threadIdx.x;
    if (t < 128) {
        uint64_t b = 0;
        for (int k = 0; k < 49; ++k)
            if (w1[t * 49 + k] < 0.0f) b |= (1ull << k);
        wb1[t] = b;
    } else if (t < 192) {
        int o = t - 128;
        uint64_t lo = 0, hi = 0;
        for (int c = 0; c < 64; ++c) if (w2[o * 128 + c]      < 0.0f) lo |= (1ull << c);
        for (int c = 0; c < 64; ++c) if (w2[o * 128 + 64 + c] < 0.0f) hi |= (1ull << c);
        w2lo[o] = lo; w2hi[o] = hi;
    }
    st1[t] = 0;
    if (t < 128) st2[t] = 0;
}

// ---- window builder: 49-bit sign window + validity mask --------------------
__device__ inline void build_window(const uint64_t* __restrict__ xb_img, int y, int x,
                                    uint64_t& sbits, uint64_t& vmask) {
    int bitpos = x + 5;               // window start x-3, +8 pad offset
    int w  = bitpos >> 6;
    int sh = bitpos & 63;
    int lo = 3 - x;   if (lo < 0) lo = 0;
    int hi = 258 - x; if (hi > 6) hi = 6;
    uint64_t hm = ((1ull << (hi - lo + 1)) - 1ull) << lo;
    sbits = 0; vmask = 0;
    #pragma unroll
    for (int dy = 0; dy < 7; ++dy) {
        int yy = y - 3 + dy;
        if (yy < 0 || yy > 255) continue;
        const uint64_t* r = xb_img + (size_t)yy * 6;
        uint64_t wA = r[w], wB = r[w + 1];
        uint64_t bits = wA >> sh;
        if (sh) bits |= wB << (64 - sh);
        bits &= 0x7Full;
        sbits |= bits << (7 * dy);
        vmask |= hm   << (7 * dy);
    }
}

// ---- K2: layer-1 BN statistics (exact integer) ------------------------------
// grid-stride over 4096 image rows; block stages a row's windows in LDS,
// each thread owns (channel, half-row) and accumulates locally.
__global__ __launch_bounds__(256) void k_stats1(const uint64_t* __restrict__ xbits,
                                                const uint64_t* __restrict__ wb1g,
                                                long long* __restrict__ st1) {
    __shared__ uint64_t sb[256];
    __shared__ uint64_t vm[256];
    __shared__ int       rs[128];
    __shared__ long long rq[128];
    int t = threadIdx.x;
    int c = t & 127, half = t >> 7;
    uint64_t wb = wb1g[c];
    int sum = 0;
    long long sumsq = 0;
    for (int row = blockIdx.x; row < 4096; row += gridDim.x) {
        int n = row >> 8, y = row & 255;
        const uint64_t* xb_img = xbits + (size_t)n * 256 * 6;
        uint64_t s, v;
        build_window(xb_img, y, t, s, v);
        sb[t] = s; vm[t] = v;
        __syncthreads();
        int base = half << 7;
        #pragma unroll 4
        for (int p = 0; p < 128; ++p) {
            uint64_t ss = sb[base + p], vv = vm[base + p];
            uint64_t d = (ss ^ wb) & vv;
            int h = __popcll(vv) - 2 * __popcll(d);
            sum += h;
            sumsq += h * h;
        }
        __syncthreads();
    }
    if (half == 1) { rs[c] = sum; rq[c] = sumsq; }
    __syncthreads();
    if (half == 0) {
        long long S = (long long)sum + rs[c];
        long long Q = sumsq + rq[c];
        atomicAdd((unsigned long long*)&st1[c],       (unsigned long long)S);
        atomicAdd((unsigned long long*)&st1[128 + c], (unsigned long long)Q);
    }
}

// ---- K3: BN1 coefficients ---------------------------------------------------
__global__ void k_fin1(const long long* __restrict__ st1,
                       const float* __restrict__ g1, const float* __restrict__ b1,
                       float* __restrict__ a1, float* __restrict__ c1) {
    int c = threadIdx.x;            // 128 threads
    double mean = (double)st1[c] / NPIX_PER_CH;
    double var  = (double)st1[128 + c] / NPIX_PER_CH - mean * mean;
    float inv = (float)((double)g1[c] / sqrt(var + 1e-5));
    a1[c] = inv;
    c1[c] = b1[c] - (float)mean * inv;
}

// ---- K4: fused conv1(sign) -> BN-sign -> conv2(1x1 binary) -> h2/2 ----------
__global__ __launch_bounds__(256) void k_conv2(const uint64_t* __restrict__ xbits,
                                               const uint64_t* __restrict__ wb1g,
                                               const float* __restrict__ a1g,
                                               const float* __restrict__ c1g,
                                               const uint64_t* __restrict__ w2log,
                                               const uint64_t* __restrict__ w2hig,
                                               int8_t* __restrict__ h2s) {
    __shared__ uint64_t wb1s[128];
    __shared__ float    a1s[128], c1s[128];
    __shared__ uint64_t w2l[64], w2h[64];
    int t = threadIdx.x;
    if (t < 128) { wb1s[t] = wb1g[t]; a1s[t] = a1g[t]; c1s[t] = c1g[t]; }
    else if (t < 192) { int o = t - 128; w2l[o] = w2log[o]; w2h[o] = w2hig[o]; }
    __syncthreads();

    int idx = blockIdx.x * 256 + t;          // 0 .. 1048575
    int n = idx >> 16, rem = idx & 65535;
    int y = rem >> 8, x = rem & 255;
    const uint64_t* xb_img = xbits + (size_t)n * 256 * 6;
    uint64_t sbits, vmask;
    build_window(xb_img, y, x, sbits, vmask);
    int nv = __popcll(vmask);

    uint64_t blo = 0, bhi = 0;
    #pragma unroll 8
    for (int cc = 0; cc < 64; ++cc) {
        uint64_t d = (sbits ^ wb1s[cc]) & vmask;
        int h = nv - 2 * __popcll(d);
        float z = fmaf(a1s[cc], (float)h, c1s[cc]);
        blo |= (uint64_t)(z < 0.0f) << cc;
    }
    #pragma unroll 8
    for (int cc = 0; cc < 64; ++cc) {
        uint64_t d = (sbits ^ wb1s[64 + cc]) & vmask;
        int h = nv - 2 * __popcll(d);
        float z = fmaf(a1s[64 + cc], (float)h, c1s[64 + cc]);
        bhi |= (uint64_t)(z < 0.0f) << cc;
    }

    size_t pbase = ((size_t)n << 22) + (size_t)rem;   // n*64*65536 + y*256+x
    #pragma unroll 8
    for (int o = 0; o < 64; ++o) {
        int m = __popcll(blo ^ w2l[o]) + __popcll(bhi ^ w2h[o]);
        h2s[pbase + ((size_t)o << 16)] = (int8_t)(64 - m);   // = h2/2
    }
}

// ---- K5: layer-2 BN statistics (on stored v = h2/2) -------------------------
__global__ __launch_bounds__(256) void k_stats2(const int8_t* __restrict__ h2s,
                                                long long* __restrict__ st2) {
    int plane = blockIdx.x;       // n*64 + o, 0..1023
    int o = plane & 63;
    int t = threadIdx.x;
    const int8_t* p = h2s + ((size_t)plane << 16) + (size_t)t * 256;
    int sum = 0, sumsq = 0;
    #pragma unroll 4
    for (int i = 0; i < 16; ++i) {
        int4 v4 = ((const int4*)p)[i];
        int wv[4] = {v4.x, v4.y, v4.z, v4.w};
        #pragma unroll
        for (int j = 0; j < 4; ++j) {
            #pragma unroll
            for (int k = 0; k < 4; ++k) {
                int b = (int)(int8_t)((unsigned)wv[j] >> (8 * k));
                sum += b;
                sumsq += b * b;
            }
        }
    }
    // wave reduce
    for (int off = 32; off; off >>= 1) {
        sum   += __shfl_down(sum, off);
        sumsq += __shfl_down(sumsq, off);
    }
    __shared__ int ws1[4], ws2[4];
    int wid = t >> 6;
    if ((t & 63) == 0) { ws1[wid] = sum; ws2[wid] = sumsq; }
    __syncthreads();
    if (t == 0) {
        long long S = 0, Q = 0;
        for (int i = 0; i < 4; ++i) { S += ws1[i]; Q += ws2[i]; }
        atomicAdd((unsigned long long*)&st2[o],      (unsigned long long)S);
        atomicAdd((unsigned long long*)&st2[64 + o], (unsigned long long)Q);
    }
}

// ---- K6: BN2 coefficients (for f2 = leaky(A2*v + C2), v = h2/2) -------------
__global__ void k_fin2(const long long* __restrict__ st2,
                       const float* __restrict__ g2, const float* __restrict__ b2,
                       float* __restrict__ a2, float* __restrict__ c2) {
    int o = threadIdx.x;            // 64 threads
    double mean = 2.0 * (double)st2[o] / NPIX_PER_CH;          // E[h2]
    double msq  = 4.0 * (double)st2[64 + o] / NPIX_PER_CH;     // E[h2^2]
    double var  = msq - mean * mean;
    double inv  = (double)g2[o] / sqrt(var + 1e-5);
    a2[o] = (float)(2.0 * inv);                 // scale applied to v = h2/2
    c2[o] = (float)((double)b2[o] - mean * inv);
}

// ---- K7: conv3 5x5 fp32, LDS-tiled ------------------------------------------
// block: 256 threads, 32x32 output tile, 8-channel LDS chunks, 4 px / thread
__global__ __launch_bounds__(256) void k_conv3(const int8_t* __restrict__ h2s,
                                               const float* __restrict__ a2g,
                                               const float* __restrict__ c2g,
                                               const float* __restrict__ w3,
                                               float* __restrict__ out) {
    __shared__ float lds[8 * 36 * 40];          // 46,080 B, row stride 40
    __shared__ float sA2[64], sC2[64];
    int t = threadIdx.x;
    if (t < 64) { sA2[t] = a2g[t]; sC2[t] = c2g[t]; }

    int bid = blockIdx.x;                        // 0..1023
    int n = bid >> 6;
    int tt = bid & 63;
    int ty0 = (tt >> 3) * 32, tx0 = (tt & 7) * 32;
    int ly = t >> 3, lxg = (t & 7) * 4;

    float acc0 = 0.f, acc1 = 0.f, acc2 = 0.f, acc3 = 0.f;

    for (int c0 = 0; c0 < 64; c0 += 8) {
        __syncthreads();
        // stage 8ch x 36x36 tile with BN+leaky applied, zero outside image
        for (int idx = t; idx < 8 * 36 * 36; idx += 256) {
            int cl = idx / 1296;
            int r2 = idx - cl * 1296;
            int rr = r2 / 36;
            int col = r2 - rr * 36;
            int gy = ty0 - 2 + rr, gx = tx0 - 2 + col;
            float f = 0.0f;
            if ((unsigned)gy < 256u && (unsigned)gx < 256u) {
                int ch = c0 + cl;
                int v = h2s[((size_t)(n * 64 + ch) << 16) + (size_t)gy * 256 + gx];
                float z = fmaf(sA2[ch], (float)v, sC2[ch]);
                f = (z < 0.0f) ? 0.5f * z : z;
            }
            lds[cl * 1440 + rr * 40 + col] = f;
        }
        __syncthreads();
        #pragma unroll
        for (int cl = 0; cl < 8; ++cl) {
            const float* wc = w3 + (size_t)(c0 + cl) * 25;
            const float* base = lds + cl * 1440;
            #pragma unroll
            for (int dy = 0; dy < 5; ++dy) {
                const float* rowp = base + (ly + dy) * 40 + lxg;
                float4 fA = *(const float4*)rowp;
                float4 fB = *(const float4*)(rowp + 4);
                float f[8] = {fA.x, fA.y, fA.z, fA.w, fB.x, fB.y, fB.z, fB.w};
                #pragma unroll
                for (int dx = 0; dx < 5; ++dx) {
                    float wv = wc[dy * 5 + dx];
                    acc0 = fmaf(wv, f[dx],     acc0);
                    acc1 = fmaf(wv, f[dx + 1], acc1);
                    acc2 = fmaf(wv, f[dx + 2], acc2);
                    acc3 = fmaf(wv, f[dx + 3], acc3);
                }
            }
        }
    }
    int gy = ty0 + ly, gx = tx0 + lxg;
    float4 r = {acc0, acc1, acc2, acc3};
    *(float4*)(out + (size_t)n * 65536 + (size_t)gy * 256 + gx) = r;
}

// ---------------------------------------------------------------------------
extern "C" void kernel_launch(void* const* d_in, const int* in_sizes, int n_in,
                              void* d_out, int out_size, void* d_ws, size_t ws_size,
                              hipStream_t stream) {
    const float* x  = (const float*)d_in[0];
    const float* w1 = (const float*)d_in[1];
    const float* g1 = (const float*)d_in[2];
    const float* b1 = (const float*)d_in[3];
    const float* w2 = (const float*)d_in[4];
    const float* g2 = (const float*)d_in[5];
    const float* b2 = (const float*)d_in[6];
    const float* w3 = (const float*)d_in[7];
    float* out = (float*)d_out;

    WS ws = carve(d_ws);

    k_pack_x<<<1024, 256, 0, stream>>>(x, ws.xbits);
    k_pack_w<<<1, 256, 0, stream>>>(w1, w2, ws.wb1, ws.w2lo, ws.w2hi, ws.st1, ws.st2);
    k_stats1<<<512, 256, 0, stream>>>(ws.xbits, ws.wb1, ws.st1);
    k_fin1<<<1, 128, 0, stream>>>(ws.st1, g1, b1, ws.a1, ws.c1);
    k_conv2<<<4096, 256, 0, stream>>>(ws.xbits, ws.wb1, ws.a1, ws.c1,
                                      ws.w2lo, ws.w2hi, ws.h2s);
    k_stats2<<<1024, 256, 0, stream>>>(ws.h2s, ws.st2);
    k_fin2<<<1, 64, 0, stream>>>(ws.st2, g2, b2, ws.a2, ws.c2);
    k_conv3<<<1024, 256, 0, stream>>>(ws.h2s, ws.a2, ws.c2, w3, out);
}

// Round 2
// 294.572 us; speedup vs baseline: 1.6781x; 1.6781x over previous
//
#include <hip/hip_runtime.h>
#include <cstdint>
#include <cstddef>

// ---------------------------------------------------------------------------
// BNN pipeline:
//  L1: conv7x7(sign(x), sign(w1)) -> BN(train) -> leaky(0.5)
//  L2: conv1x1(sign(.), sign(w2)) -> BN(train) -> leaky(0.5)
//  L3: conv5x5 fp32 (64->1)
// Shapes: x (16,1,256,256), out (16,1,256,256)
//
// h2s layout (PADDED in x): int8 [16*64][256][264], col p maps to x = p-2.
//   data at p=2..257; pads p=0,1,258..263 are zeroed by k_conv2 edge threads.
//   plane stride = 256*264 = 67584 bytes.
// ---------------------------------------------------------------------------

#define NPIX_PER_CH (16.0 * 256.0 * 256.0)
#define PLANE_BYTES 67584      // 256*264
#define ROW_BYTES   264

struct WS {
    int8_t*   h2s;
    uint64_t* xbits;
    uint64_t* wb1;
    uint64_t* w2lo;
    uint64_t* w2hi;
    long long* st1;
    long long* st2;
    float* a1; float* c1;
    float* a2; float* c2;
};

static inline WS carve(void* d_ws) {
    WS w;
    uint8_t* p = (uint8_t*)d_ws;
    w.h2s   = (int8_t*)p;              p += (size_t)16 * 64 * PLANE_BYTES;  // 69,206,016
    w.xbits = (uint64_t*)p;            p += (size_t)16 * 256 * 6 * 8;
    w.wb1   = (uint64_t*)p;            p += 128 * 8;
    w.w2lo  = (uint64_t*)p;            p += 64 * 8;
    w.w2hi  = (uint64_t*)p;            p += 64 * 8;
    w.st1   = (long long*)p;           p += 256 * 8;
    w.st2   = (long long*)p;           p += 128 * 8;
    w.a1    = (float*)p;               p += 128 * 4;
    w.c1    = (float*)p;               p += 128 * 4;
    w.a2    = (float*)p;               p += 64 * 4;
    w.c2    = (float*)p;               p += 64 * 4;
    return w;
}

// ---- K0: pack sign bits of x into padded per-row words ---------------------
__global__ __launch_bounds__(256) void k_pack_x(const float* __restrict__ x,
                                                uint64_t* __restrict__ xbits) {
    int rowId = blockIdx.x * 4 + (threadIdx.x >> 6);
    int lane  = threadIdx.x & 63;
    const float* row = x + (size_t)rowId * 256;
    uint64_t b0 = __ballot(row[0 * 64 + lane] < 0.0f);
    uint64_t b1 = __ballot(row[1 * 64 + lane] < 0.0f);
    uint64_t b2 = __ballot(row[2 * 64 + lane] < 0.0f);
    uint64_t b3 = __ballot(row[3 * 64 + lane] < 0.0f);
    if (lane == 0) {
        uint64_t* o = xbits + (size_t)rowId * 6;
        o[0] = b0 << 8;
        o[1] = (b0 >> 56) | (b1 << 8);
        o[2] = (b1 >> 56) | (b2 << 8);
        o[3] = (b2 >> 56) | (b3 << 8);
        o[4] = b3 >> 56;
        o[5] = 0;
    }
}

// ---- K1: pack weight sign bits, zero stat accumulators ---------------------
__global__ void k_pack_w(const float* __restrict__ w1, const float* __restrict__ w2,
                         uint64_t* __restrict__ wb1, uint64_t* __restrict__ w2lo,
                         uint64_t* __restrict__ w2hi,
                         long long* __restrict__ st1, long long* __restrict__ st2) {
    int t = threadIdx.x;
    if (t < 128) {
        uint64_t b = 0;
        for (int k = 0; k < 49; ++k)
            if (w1[t * 49 + k] < 0.0f) b |= (1ull << k);
        wb1[t] = b;
    } else if (t < 192) {
        int o = t - 128;
        uint64_t lo = 0, hi = 0;
        for (int c = 0; c < 64; ++c) if (w2[o * 128 + c]      < 0.0f) lo |= (1ull << c);
        for (int c = 0; c < 64; ++c) if (w2[o * 128 + 64 + c] < 0.0f) hi |= (1ull << c);
        w2lo[o] = lo; w2hi[o] = hi;
    }
    st1[t] = 0;
    if (t < 128) st2[t] = 0;
}

// ---- window builder: 49-bit sign window + validity mask --------------------
__device__ inline void build_window(const uint64_t* __restrict__ xb_img, int y, int x,
                                    uint64_t& sbits, uint64_t& vmask) {
    int bitpos = x + 5;
    int w  = bitpos >> 6;
    int sh = bitpos & 63;
    int lo = 3 - x;   if (lo < 0) lo = 0;
    int hi = 258 - x; if (hi > 6) hi = 6;
    uint64_t hm = ((1ull << (hi - lo + 1)) - 1ull) << lo;
    sbits = 0; vmask = 0;
    #pragma unroll
    for (int dy = 0; dy < 7; ++dy) {
        int yy = y - 3 + dy;
        if (yy < 0 || yy > 255) continue;
        const uint64_t* r = xb_img + (size_t)yy * 6;
        uint64_t wA = r[w], wB = r[w + 1];
        uint64_t bits = wA >> sh;
        if (sh) bits |= wB << (64 - sh);
        bits &= 0x7Full;
        sbits |= bits << (7 * dy);
        vmask |= hm   << (7 * dy);
    }
}

// ---- K2: layer-1 BN statistics (exact integer) ------------------------------
__global__ __launch_bounds__(256) void k_stats1(const uint64_t* __restrict__ xbits,
                                                const uint64_t* __restrict__ wb1g,
                                                long long* __restrict__ st1) {
    __shared__ uint64_t sb[256];
    __shared__ uint64_t vm[256];
    __shared__ int       rs[128];
    __shared__ long long rq[128];
    int t = threadIdx.x;
    int c = t & 127, half = t >> 7;
    uint64_t wb = wb1g[c];
    int sum = 0;
    long long sumsq = 0;
    for (int row = blockIdx.x; row < 4096; row += gridDim.x) {
        int n = row >> 8, y = row & 255;
        const uint64_t* xb_img = xbits + (size_t)n * 256 * 6;
        uint64_t s, v;
        build_window(xb_img, y, t, s, v);
        sb[t] = s; vm[t] = v;
        __syncthreads();
        int base = half << 7;
        #pragma unroll 4
        for (int p = 0; p < 128; ++p) {
            uint64_t ss = sb[base + p], vv = vm[base + p];
            uint64_t d = (ss ^ wb) & vv;
            int h = __popcll(vv) - 2 * __popcll(d);
            sum += h;
            sumsq += h * h;
        }
        __syncthreads();
    }
    if (half == 1) { rs[c] = sum; rq[c] = sumsq; }
    __syncthreads();
    if (half == 0) {
        long long S = (long long)sum + rs[c];
        long long Q = sumsq + rq[c];
        atomicAdd((unsigned long long*)&st1[c],       (unsigned long long)S);
        atomicAdd((unsigned long long*)&st1[128 + c], (unsigned long long)Q);
    }
}

// ---- K3: BN1 coefficients ---------------------------------------------------
__global__ void k_fin1(const long long* __restrict__ st1,
                       const float* __restrict__ g1, const float* __restrict__ b1,
                       float* __restrict__ a1, float* __restrict__ c1) {
    int c = threadIdx.x;
    double mean = (double)st1[c] / NPIX_PER_CH;
    double var  = (double)st1[128 + c] / NPIX_PER_CH - mean * mean;
    float inv = (float)((double)g1[c] / sqrt(var + 1e-5));
    a1[c] = inv;
    c1[c] = b1[c] - (float)mean * inv;
}

// ---- K4: fused conv1(sign) -> BN-sign -> conv2(1x1 binary) -> h2/2 ----------
__global__ __launch_bounds__(256) void k_conv2(const uint64_t* __restrict__ xbits,
                                               const uint64_t* __restrict__ wb1g,
                                               const float* __restrict__ a1g,
                                               const float* __restrict__ c1g,
                                               const uint64_t* __restrict__ w2log,
                                               const uint64_t* __restrict__ w2hig,
                                               int8_t* __restrict__ h2s) {
    __shared__ uint64_t wb1s[128];
    __shared__ float    a1s[128], c1s[128];
    __shared__ uint64_t w2l[64], w2h[64];
    int t = threadIdx.x;
    if (t < 128) { wb1s[t] = wb1g[t]; a1s[t] = a1g[t]; c1s[t] = c1g[t]; }
    else if (t < 192) { int o = t - 128; w2l[o] = w2log[o]; w2h[o] = w2hig[o]; }
    __syncthreads();

    int idx = blockIdx.x * 256 + t;
    int n = idx >> 16, rem = idx & 65535;
    int y = rem >> 8, x = rem & 255;
    const uint64_t* xb_img = xbits + (size_t)n * 256 * 6;
    uint64_t sbits, vmask;
    build_window(xb_img, y, x, sbits, vmask);
    int nv = __popcll(vmask);

    uint64_t blo = 0, bhi = 0;
    #pragma unroll 8
    for (int cc = 0; cc < 64; ++cc) {
        uint64_t d = (sbits ^ wb1s[cc]) & vmask;
        int h = nv - 2 * __popcll(d);
        float z = fmaf(a1s[cc], (float)h, c1s[cc]);
        blo |= (uint64_t)(z < 0.0f) << cc;
    }
    #pragma unroll 8
    for (int cc = 0; cc < 64; ++cc) {
        uint64_t d = (sbits ^ wb1s[64 + cc]) & vmask;
        int h = nv - 2 * __popcll(d);
        float z = fmaf(a1s[64 + cc], (float)h, c1s[64 + cc]);
        bhi |= (uint64_t)(z < 0.0f) << cc;
    }

    size_t base = (size_t)(n * 64) * PLANE_BYTES + (size_t)y * ROW_BYTES;
    #pragma unroll 8
    for (int o = 0; o < 64; ++o) {
        int m = __popcll(blo ^ w2l[o]) + __popcll(bhi ^ w2h[o]);
        h2s[base + (size_t)o * PLANE_BYTES + 2 + x] = (int8_t)(64 - m);
    }
    // zero the x-pad bytes (p = 0,1 and 258..263) so conv3/stats2 need no checks
    if (x == 0) {
        #pragma unroll 8
        for (int o = 0; o < 64; ++o)
            *(short*)(h2s + base + (size_t)o * PLANE_BYTES) = 0;
    }
    if (x == 255) {
        #pragma unroll 8
        for (int o = 0; o < 64; ++o) {
            int8_t* r = h2s + base + (size_t)o * PLANE_BYTES;
            *(short*)(r + 258) = 0;
            *(int*)(r + 260) = 0;
        }
    }
}

// ---- K5: layer-2 BN statistics (on stored v = h2/2, padded layout) ----------
// reads whole plane incl. zero pads (zeros don't affect sum/sumsq)
__global__ __launch_bounds__(256) void k_stats2(const int8_t* __restrict__ h2s,
                                                long long* __restrict__ st2) {
    int plane = blockIdx.x;       // n*64 + o, 0..1023
    int o = plane & 63;
    int t = threadIdx.x;
    const int4* p = (const int4*)(h2s + (size_t)plane * PLANE_BYTES);
    int sum = 0, sumsq = 0;
    for (int si = t; si < 4224; si += 256) {     // 4224 = 67584/16
        int4 v4 = p[si];
        int wv[4] = {v4.x, v4.y, v4.z, v4.w};
        #pragma unroll
        for (int j = 0; j < 4; ++j) {
            #pragma unroll
            for (int k = 0; k < 4; ++k) {
                int b = (int)(int8_t)((unsigned)wv[j] >> (8 * k));
                sum += b;
                sumsq += b * b;
            }
        }
    }
    for (int off = 32; off; off >>= 1) {
        sum   += __shfl_down(sum, off);
        sumsq += __shfl_down(sumsq, off);
    }
    __shared__ int ws1[4], ws2[4];
    int wid = t >> 6;
    if ((t & 63) == 0) { ws1[wid] = sum; ws2[wid] = sumsq; }
    __syncthreads();
    if (t == 0) {
        long long S = 0, Q = 0;
        for (int i = 0; i < 4; ++i) { S += ws1[i]; Q += ws2[i]; }
        atomicAdd((unsigned long long*)&st2[o],      (unsigned long long)S);
        atomicAdd((unsigned long long*)&st2[64 + o], (unsigned long long)Q);
    }
}

// ---- K6: BN2 coefficients (for f2 = leaky(A2*v + C2), v = h2/2) -------------
__global__ void k_fin2(const long long* __restrict__ st2,
                       const float* __restrict__ g2, const float* __restrict__ b2,
                       float* __restrict__ a2, float* __restrict__ c2) {
    int o = threadIdx.x;
    double mean = 2.0 * (double)st2[o] / NPIX_PER_CH;
    double msq  = 4.0 * (double)st2[64 + o] / NPIX_PER_CH;
    double var  = msq - mean * mean;
    double inv  = (double)g2[o] / sqrt(var + 1e-5);
    a2[o] = (float)(2.0 * inv);
    c2[o] = (float)((double)b2[o] - mean * inv);
}

// ---- K7: conv3 5x5 fp32 — register-blocked 2y x 4x per thread ---------------
// grid: 16 n * 8 ytiles * 4 xtiles = 512 blocks; tile 32y x 64x; 256 threads.
// LDS: 8ch x 36rows x 68cols f32 (78336 B) -> exactly 2 blocks/CU.
__global__ __launch_bounds__(256, 2) void k_conv3(const int8_t* __restrict__ h2s,
                                                  const float* __restrict__ a2g,
                                                  const float* __restrict__ c2g,
                                                  const float* __restrict__ w3,
                                                  float* __restrict__ out) {
    __shared__ __align__(16) float lds[8 * 36 * 68];   // 78336 B
    __shared__ float sA2[64], sC2[64];
    int t = threadIdx.x;
    if (t < 64) { sA2[t] = a2g[t]; sC2[t] = c2g[t]; }
    __syncthreads();

    int bid = blockIdx.x;
    int n   = bid >> 5;
    int yt  = (bid >> 2) & 7;
    int xt  = bid & 3;
    int ty0 = yt * 32, tx0 = xt * 64;
    int ty  = t >> 4, tx = t & 15;          // thread computes rows 2ty,2ty+1; cols tx*4..+3
    int n64 = n * 64;

    float acc[2][4] = {{0.f,0.f,0.f,0.f},{0.f,0.f,0.f,0.f}};

    for (int c0 = 0; c0 < 64; c0 += 8) {
        __syncthreads();
        // stage 8ch x 36 x 68 (17 int-quads per row); window col p = tx0 + qc*4
        for (int si = t; si < 4896; si += 256) {     // 4896 = 8*36*17
            int cl  = si / 612;                      // 612 = 36*17
            int rem = si - cl * 612;
            int rr  = rem / 17;
            int qc  = rem - rr * 17;
            int gy  = ty0 - 2 + rr;
            int ch  = c0 + cl;
            float a = sA2[ch], c = sC2[ch];
            float4 fo = {0.f, 0.f, 0.f, 0.f};
            if ((unsigned)gy < 256u) {
                int v = *(const int*)(h2s + (size_t)(n64 + ch) * PLANE_BYTES
                                          + (size_t)gy * ROW_BYTES + tx0 + qc * 4);
                float z0 = fmaf(a, (float)(int)(int8_t)(v),        c);
                float z1 = fmaf(a, (float)(int)(int8_t)(v >> 8),   c);
                float z2 = fmaf(a, (float)(int)(int8_t)(v >> 16),  c);
                float z3 = fmaf(a, (float)(int)(int8_t)(v >> 24),  c);
                fo.x = fmaxf(z0, 0.5f * z0);
                fo.y = fmaxf(z1, 0.5f * z1);
                fo.z = fmaxf(z2, 0.5f * z2);
                fo.w = fmaxf(z3, 0.5f * z3);
            }
            *(float4*)&lds[cl * 2448 + rr * 68 + qc * 4] = fo;
        }
        __syncthreads();

        for (int cl = 0; cl < 8; ++cl) {
            const float* wc = w3 + (size_t)(c0 + cl) * 25;   // uniform -> s_loads
            const float* base = &lds[cl * 2448 + (2 * ty) * 68 + tx * 4];
            #pragma unroll
            for (int rr = 0; rr < 6; ++rr) {
                float4 A = *(const float4*)(base + rr * 68);
                float4 B = *(const float4*)(base + rr * 68 + 4);
                float f[8] = {A.x, A.y, A.z, A.w, B.x, B.y, B.z, B.w};
                if (rr <= 4) {                     // output row 0, dy = rr
                    #pragma unroll
                    for (int dx = 0; dx < 5; ++dx) {
                        float wv = wc[rr * 5 + dx];
                        acc[0][0] = fmaf(wv, f[dx],     acc[0][0]);
                        acc[0][1] = fmaf(wv, f[dx + 1], acc[0][1]);
                        acc[0][2] = fmaf(wv, f[dx + 2], acc[0][2]);
                        acc[0][3] = fmaf(wv, f[dx + 3], acc[0][3]);
                    }
                }
                if (rr >= 1) {                     // output row 1, dy = rr-1
                    #pragma unroll
                    for (int dx = 0; dx < 5; ++dx) {
                        float wv = wc[(rr - 1) * 5 + dx];
                        acc[1][0] = fmaf(wv, f[dx],     acc[1][0]);
                        acc[1][1] = fmaf(wv, f[dx + 1], acc[1][1]);
                        acc[1][2] = fmaf(wv, f[dx + 2], acc[1][2]);
                        acc[1][3] = fmaf(wv, f[dx + 3], acc[1][3]);
                    }
                }
            }
        }
    }

    int oy = ty0 + 2 * ty;
    int ox = tx0 + tx * 4;
    float4 r0 = {acc[0][0], acc[0][1], acc[0][2], acc[0][3]};
    float4 r1 = {acc[1][0], acc[1][1], acc[1][2], acc[1][3]};
    *(float4*)(out + (size_t)n * 65536 + (size_t)oy * 256 + ox)       = r0;
    *(float4*)(out + (size_t)n * 65536 + (size_t)(oy + 1) * 256 + ox) = r1;
}

// ---------------------------------------------------------------------------
extern "C" void kernel_launch(void* const* d_in, const int* in_sizes, int n_in,
                              void* d_out, int out_size, void* d_ws, size_t ws_size,
                              hipStream_t stream) {
    const float* x  = (const float*)d_in[0];
    const float* w1 = (const float*)d_in[1];
    const float* g1 = (const float*)d_in[2];
    const float* b1 = (const float*)d_in[3];
    const float* w2 = (const float*)d_in[4];
    const float* g2 = (const float*)d_in[5];
    const float* b2 = (const float*)d_in[6];
    const float* w3 = (const float*)d_in[7];
    float* out = (float*)d_out;

    WS ws = carve(d_ws);

    k_pack_x<<<1024, 256, 0, stream>>>(x, ws.xbits);
    k_pack_w<<<1, 256, 0, stream>>>(w1, w2, ws.wb1, ws.w2lo, ws.w2hi, ws.st1, ws.st2);
    k_stats1<<<512, 256, 0, stream>>>(ws.xbits, ws.wb1, ws.st1);
    k_fin1<<<1, 128, 0, stream>>>(ws.st1, g1, b1, ws.a1, ws.c1);
    k_conv2<<<4096, 256, 0, stream>>>(ws.xbits, ws.wb1, ws.a1, ws.c1,
                                      ws.w2lo, ws.w2hi, ws.h2s);
    k_stats2<<<1024, 256, 0, stream>>>(ws.h2s, ws.st2);
    k_fin2<<<1, 64, 0, stream>>>(ws.st2, g2, b2, ws.a2, ws.c2);
    k_conv3<<<512, 256, 0, stream>>>(ws.h2s, ws.a2, ws.c2, w3, out);
}

// Round 3
// 278.363 us; speedup vs baseline: 1.7758x; 1.0582x over previous
//
#include <hip/hip_runtime.h>
#include <cstdint>
#include <cstddef>

// ---------------------------------------------------------------------------
// BNN pipeline:
//  L1: conv7x7(sign(x), sign(w1)) -> BN(train) -> leaky(0.5)
//  L2: conv1x1(sign(.), sign(w2)) -> BN(train) -> leaky(0.5)
//  L3: conv5x5 fp32 (64->1)
// Shapes: x (16,1,256,256), out (16,1,256,256)
//
// h2s layout (PADDED in x): int8 [16*64][256][264], col p maps to x = p-2.
//   data at p=2..257; pads p=0,1,258..263 are zeroed by k_conv2 edge threads.
//   plane stride = 256*264 = 67584 bytes.
//
// conv3: 4 channel-groups x 16ch; partial sums accumulated into d_out as
// int32 fixed-point (x 2^18) via atomicAdd (deterministic), then finalized.
// ---------------------------------------------------------------------------

#define NPIX_PER_CH (16.0 * 256.0 * 256.0)
#define PLANE_BYTES 67584      // 256*264
#define ROW_BYTES   264
#define FXSCALE     262144.0f              // 2^18
#define FXINV       3.814697265625e-06f    // 2^-18

struct WS {
    int8_t*   h2s;
    uint64_t* xbits;
    uint64_t* wb1;
    uint64_t* w2lo;
    uint64_t* w2hi;
    long long* st1;
    long long* st2;
    float* a1; float* c1;
    float* a2; float* c2;
};

static inline WS carve(void* d_ws) {
    WS w;
    uint8_t* p = (uint8_t*)d_ws;
    w.h2s   = (int8_t*)p;              p += (size_t)16 * 64 * PLANE_BYTES;  // 69,206,016
    w.xbits = (uint64_t*)p;            p += (size_t)16 * 256 * 6 * 8;
    w.wb1   = (uint64_t*)p;            p += 128 * 8;
    w.w2lo  = (uint64_t*)p;            p += 64 * 8;
    w.w2hi  = (uint64_t*)p;            p += 64 * 8;
    w.st1   = (long long*)p;           p += 256 * 8;
    w.st2   = (long long*)p;           p += 128 * 8;
    w.a1    = (float*)p;               p += 128 * 4;
    w.c1    = (float*)p;               p += 128 * 4;
    w.a2    = (float*)p;               p += 64 * 4;
    w.c2    = (float*)p;               p += 64 * 4;
    return w;
}

// ---- K0: pack sign bits of x into padded per-row words ---------------------
__global__ __launch_bounds__(256) void k_pack_x(const float* __restrict__ x,
                                                uint64_t* __restrict__ xbits) {
    int rowId = blockIdx.x * 4 + (threadIdx.x >> 6);
    int lane  = threadIdx.x & 63;
    const float* row = x + (size_t)rowId * 256;
    uint64_t b0 = __ballot(row[0 * 64 + lane] < 0.0f);
    uint64_t b1 = __ballot(row[1 * 64 + lane] < 0.0f);
    uint64_t b2 = __ballot(row[2 * 64 + lane] < 0.0f);
    uint64_t b3 = __ballot(row[3 * 64 + lane] < 0.0f);
    if (lane == 0) {
        uint64_t* o = xbits + (size_t)rowId * 6;
        o[0] = b0 << 8;
        o[1] = (b0 >> 56) | (b1 << 8);
        o[2] = (b1 >> 56) | (b2 << 8);
        o[3] = (b2 >> 56) | (b3 << 8);
        o[4] = b3 >> 56;
        o[5] = 0;
    }
}

// ---- K1: pack weight sign bits, zero stat accumulators ---------------------
__global__ void k_pack_w(const float* __restrict__ w1, const float* __restrict__ w2,
                         uint64_t* __restrict__ wb1, uint64_t* __restrict__ w2lo,
                         uint64_t* __restrict__ w2hi,
                         long long* __restrict__ st1, long long* __restrict__ st2) {
    int t = threadIdx.x;
    if (t < 128) {
        uint64_t b = 0;
        for (int k = 0; k < 49; ++k)
            if (w1[t * 49 + k] < 0.0f) b |= (1ull << k);
        wb1[t] = b;
    } else if (t < 192) {
        int o = t - 128;
        uint64_t lo = 0, hi = 0;
        for (int c = 0; c < 64; ++c) if (w2[o * 128 + c]      < 0.0f) lo |= (1ull << c);
        for (int c = 0; c < 64; ++c) if (w2[o * 128 + 64 + c] < 0.0f) hi |= (1ull << c);
        w2lo[o] = lo; w2hi[o] = hi;
    }
    st1[t] = 0;
    if (t < 128) st2[t] = 0;
}

// ---- window builder: 49-bit sign window + validity mask --------------------
__device__ inline void build_window(const uint64_t* __restrict__ xb_img, int y, int x,
                                    uint64_t& sbits, uint64_t& vmask) {
    int bitpos = x + 5;
    int w  = bitpos >> 6;
    int sh = bitpos & 63;
    int lo = 3 - x;   if (lo < 0) lo = 0;
    int hi = 258 - x; if (hi > 6) hi = 6;
    uint64_t hm = ((1ull << (hi - lo + 1)) - 1ull) << lo;
    sbits = 0; vmask = 0;
    #pragma unroll
    for (int dy = 0; dy < 7; ++dy) {
        int yy = y - 3 + dy;
        if (yy < 0 || yy > 255) continue;
        const uint64_t* r = xb_img + (size_t)yy * 6;
        uint64_t wA = r[w], wB = r[w + 1];
        uint64_t bits = wA >> sh;
        if (sh) bits |= wB << (64 - sh);
        bits &= 0x7Full;
        sbits |= bits << (7 * dy);
        vmask |= hm   << (7 * dy);
    }
}

// ---- K2: layer-1 BN statistics (exact integer) ------------------------------
__global__ __launch_bounds__(256) void k_stats1(const uint64_t* __restrict__ xbits,
                                                const uint64_t* __restrict__ wb1g,
                                                long long* __restrict__ st1) {
    __shared__ uint64_t sb[256];
    __shared__ uint64_t vm[256];
    __shared__ int       rs[128];
    __shared__ long long rq[128];
    int t = threadIdx.x;
    int c = t & 127, half = t >> 7;
    uint64_t wb = wb1g[c];
    int sum = 0;
    long long sumsq = 0;
    for (int row = blockIdx.x; row < 4096; row += gridDim.x) {
        int n = row >> 8, y = row & 255;
        const uint64_t* xb_img = xbits + (size_t)n * 256 * 6;
        uint64_t s, v;
        build_window(xb_img, y, t, s, v);
        sb[t] = s; vm[t] = v;
        __syncthreads();
        int base = half << 7;
        #pragma unroll 4
        for (int p = 0; p < 128; ++p) {
            uint64_t ss = sb[base + p], vv = vm[base + p];
            uint64_t d = (ss ^ wb) & vv;
            int h = __popcll(vv) - 2 * __popcll(d);
            sum += h;
            sumsq += h * h;
        }
        __syncthreads();
    }
    if (half == 1) { rs[c] = sum; rq[c] = sumsq; }
    __syncthreads();
    if (half == 0) {
        long long S = (long long)sum + rs[c];
        long long Q = sumsq + rq[c];
        atomicAdd((unsigned long long*)&st1[c],       (unsigned long long)S);
        atomicAdd((unsigned long long*)&st1[128 + c], (unsigned long long)Q);
    }
}

// ---- K3: BN1 coefficients ---------------------------------------------------
__global__ void k_fin1(const long long* __restrict__ st1,
                       const float* __restrict__ g1, const float* __restrict__ b1,
                       float* __restrict__ a1, float* __restrict__ c1) {
    int c = threadIdx.x;
    double mean = (double)st1[c] / NPIX_PER_CH;
    double var  = (double)st1[128 + c] / NPIX_PER_CH - mean * mean;
    float inv = (float)((double)g1[c] / sqrt(var + 1e-5));
    a1[c] = inv;
    c1[c] = b1[c] - (float)mean * inv;
}

// ---- K4: fused conv1(sign) -> BN-sign -> conv2(1x1 binary) -> h2/2 ----------
__global__ __launch_bounds__(256) void k_conv2(const uint64_t* __restrict__ xbits,
                                               const uint64_t* __restrict__ wb1g,
                                               const float* __restrict__ a1g,
                                               const float* __restrict__ c1g,
                                               const uint64_t* __restrict__ w2log,
                                               const uint64_t* __restrict__ w2hig,
                                               int8_t* __restrict__ h2s) {
    __shared__ uint64_t wb1s[128];
    __shared__ float    a1s[128], c1s[128];
    __shared__ uint64_t w2l[64], w2h[64];
    int t = threadIdx.x;
    if (t < 128) { wb1s[t] = wb1g[t]; a1s[t] = a1g[t]; c1s[t] = c1g[t]; }
    else if (t < 192) { int o = t - 128; w2l[o] = w2log[o]; w2h[o] = w2hig[o]; }
    __syncthreads();

    int idx = blockIdx.x * 256 + t;
    int n = idx >> 16, rem = idx & 65535;
    int y = rem >> 8, x = rem & 255;
    const uint64_t* xb_img = xbits + (size_t)n * 256 * 6;
    uint64_t sbits, vmask;
    build_window(xb_img, y, x, sbits, vmask);
    int nv = __popcll(vmask);

    uint64_t blo = 0, bhi = 0;
    #pragma unroll 8
    for (int cc = 0; cc < 64; ++cc) {
        uint64_t d = (sbits ^ wb1s[cc]) & vmask;
        int h = nv - 2 * __popcll(d);
        float z = fmaf(a1s[cc], (float)h, c1s[cc]);
        blo |= (uint64_t)(z < 0.0f) << cc;
    }
    #pragma unroll 8
    for (int cc = 0; cc < 64; ++cc) {
        uint64_t d = (sbits ^ wb1s[64 + cc]) & vmask;
        int h = nv - 2 * __popcll(d);
        float z = fmaf(a1s[64 + cc], (float)h, c1s[64 + cc]);
        bhi |= (uint64_t)(z < 0.0f) << cc;
    }

    size_t base = (size_t)(n * 64) * PLANE_BYTES + (size_t)y * ROW_BYTES;
    #pragma unroll 8
    for (int o = 0; o < 64; ++o) {
        int m = __popcll(blo ^ w2l[o]) + __popcll(bhi ^ w2h[o]);
        h2s[base + (size_t)o * PLANE_BYTES + 2 + x] = (int8_t)(64 - m);
    }
    // zero the x-pad bytes (p = 0,1 and 258..263) so conv3/stats2 need no checks
    if (x == 0) {
        #pragma unroll 8
        for (int o = 0; o < 64; ++o)
            *(short*)(h2s + base + (size_t)o * PLANE_BYTES) = 0;
    }
    if (x == 255) {
        #pragma unroll 8
        for (int o = 0; o < 64; ++o) {
            int8_t* r = h2s + base + (size_t)o * PLANE_BYTES;
            *(short*)(r + 258) = 0;
            *(int*)(r + 260) = 0;
        }
    }
}

// ---- K5: layer-2 BN statistics (on stored v = h2/2, padded layout) ----------
__global__ __launch_bounds__(256) void k_stats2(const int8_t* __restrict__ h2s,
                                                long long* __restrict__ st2) {
    int plane = blockIdx.x;       // n*64 + o, 0..1023
    int o = plane & 63;
    int t = threadIdx.x;
    const int4* p = (const int4*)(h2s + (size_t)plane * PLANE_BYTES);
    int sum = 0, sumsq = 0;
    for (int si = t; si < 4224; si += 256) {     // 4224 = 67584/16
        int4 v4 = p[si];
        int wv[4] = {v4.x, v4.y, v4.z, v4.w};
        #pragma unroll
        for (int j = 0; j < 4; ++j) {
            #pragma unroll
            for (int k = 0; k < 4; ++k) {
                int b = (int)(int8_t)((unsigned)wv[j] >> (8 * k));
                sum += b;
                sumsq += b * b;
            }
        }
    }
    for (int off = 32; off; off >>= 1) {
        sum   += __shfl_down(sum, off);
        sumsq += __shfl_down(sumsq, off);
    }
    __shared__ int ws1[4], ws2[4];
    int wid = t >> 6;
    if ((t & 63) == 0) { ws1[wid] = sum; ws2[wid] = sumsq; }
    __syncthreads();
    if (t == 0) {
        long long S = 0, Q = 0;
        for (int i = 0; i < 4; ++i) { S += ws1[i]; Q += ws2[i]; }
        atomicAdd((unsigned long long*)&st2[o],      (unsigned long long)S);
        atomicAdd((unsigned long long*)&st2[64 + o], (unsigned long long)Q);
    }
}

// ---- K6: BN2 coefficients (for f2 = leaky(A2*v + C2), v = h2/2) -------------
__global__ void k_fin2(const long long* __restrict__ st2,
                       const float* __restrict__ g2, const float* __restrict__ b2,
                       float* __restrict__ a2, float* __restrict__ c2) {
    int o = threadIdx.x;
    double mean = 2.0 * (double)st2[o] / NPIX_PER_CH;
    double msq  = 4.0 * (double)st2[64 + o] / NPIX_PER_CH;
    double var  = msq - mean * mean;
    double inv  = (double)g2[o] / sqrt(var + 1e-5);
    a2[o] = (float)(2.0 * inv);
    c2[o] = (float)((double)b2[o] - mean * inv);
}

// ---- K7a: zero d_out (int accumulator) --------------------------------------
__global__ __launch_bounds__(256) void k_zero3(int4* __restrict__ o) {
    int i = blockIdx.x * 256 + threadIdx.x;      // 256 blocks -> 65536 threads
    #pragma unroll
    for (int j = 0; j < 4; ++j)
        o[(size_t)i * 4 + j] = make_int4(0, 0, 0, 0);
}

// ---- K7: conv3 5x5 fp32 — channel-split, 64x64 tile, 4y x 4x per thread -----
// grid: 4 chan-groups x (16 n * 4 yt * 4 xt) = 1024 blocks; 256 threads.
// LDS: 2ch x 68 x 68 f32 (36992 B) -> 4 blocks/CU, ~16 waves/CU.
// Output: int32 fixed-point atomicAdd (deterministic; exact integer sums).
__global__ __launch_bounds__(256, 4) void k_conv3(const int8_t* __restrict__ h2s,
                                                  const float* __restrict__ a2g,
                                                  const float* __restrict__ c2g,
                                                  const float* __restrict__ w3,
                                                  int* __restrict__ outi) {
    __shared__ __align__(16) float lds[2 * 68 * 68];   // 36992 B
    __shared__ float sA2[16], sC2[16];
    int t = threadIdx.x;
    int bid = blockIdx.x;
    int cg   = bid >> 8;                // 0..3
    int rest = bid & 255;
    int n  = rest >> 4;
    int yt = (rest >> 2) & 3;
    int xt = rest & 3;
    int ty0 = yt * 64, tx0 = xt * 64;
    int cgbase = cg * 16;
    if (t < 16) { sA2[t] = a2g[cgbase + t]; sC2[t] = c2g[cgbase + t]; }

    int ty = t >> 4, tx = t & 15;       // outputs rows ty0+4ty..+3, cols tx0+4tx..+3
    int n64 = n * 64;

    float acc[4][4] = {{0.f,0.f,0.f,0.f},{0.f,0.f,0.f,0.f},
                       {0.f,0.f,0.f,0.f},{0.f,0.f,0.f,0.f}};

    for (int k = 0; k < 8; ++k) {       // 8 chunks x 2 channels
        __syncthreads();                // guards lds reuse + sA2 on first iter
        // stage 2ch x 68rows x 17quads = 2312 int-quads; lds f4 index == si
        for (int si = t; si < 2312; si += 256) {
            int cl  = si / 1156;
            int rem = si - cl * 1156;
            int rr  = rem / 17;
            int qc  = rem - rr * 17;
            int gy  = ty0 - 2 + rr;
            int lc  = 2 * k + cl;
            float a = sA2[lc], c = sC2[lc];
            float4 fo = {0.f, 0.f, 0.f, 0.f};
            if ((unsigned)gy < 256u) {
                int v = *(const int*)(h2s + (size_t)(n64 + cgbase + lc) * PLANE_BYTES
                                          + (size_t)gy * ROW_BYTES + tx0 + qc * 4);
                float z0 = fmaf(a, (float)(int)(int8_t)(v),        c);
                float z1 = fmaf(a, (float)(int)(int8_t)(v >> 8),   c);
                float z2 = fmaf(a, (float)(int)(int8_t)(v >> 16),  c);
                float z3 = fmaf(a, (float)(int)(int8_t)(v >> 24),  c);
                fo.x = fmaxf(z0, 0.5f * z0);
                fo.y = fmaxf(z1, 0.5f * z1);
                fo.z = fmaxf(z2, 0.5f * z2);
                fo.w = fmaxf(z3, 0.5f * z3);
            }
            *(float4*)&lds[si * 4] = fo;     // linear: cl*4624 + rr*68 + qc*4
        }
        __syncthreads();

        #pragma unroll
        for (int cl = 0; cl < 2; ++cl) {
            const float* wc = w3 + (size_t)(cgbase + 2 * k + cl) * 25;  // uniform
            const float* base = &lds[cl * 4624 + (4 * ty) * 68 + 4 * tx];
            #pragma unroll
            for (int rr = 0; rr < 8; ++rr) {           // input rows 4ty .. 4ty+7
                float4 A = *(const float4*)(base + rr * 68);
                float4 B = *(const float4*)(base + rr * 68 + 4);
                float f[8] = {A.x, A.y, A.z, A.w, B.x, B.y, B.z, B.w};
                #pragma unroll
                for (int dyp = 0; dyp < 5; ++dyp) {
                    int r = rr - dyp;                  // output row index
                    if (r >= 0 && r < 4) {
                        #pragma unroll
                        for (int dx = 0; dx < 5; ++dx) {
                            float wv = wc[dyp * 5 + dx];
                            acc[r][0] = fmaf(wv, f[dx],     acc[r][0]);
                            acc[r][1] = fmaf(wv, f[dx + 1], acc[r][1]);
                            acc[r][2] = fmaf(wv, f[dx + 2], acc[r][2]);
                            acc[r][3] = fmaf(wv, f[dx + 3], acc[r][3]);
                        }
                    }
                }
            }
        }
    }

    int ox = tx0 + 4 * tx;
    #pragma unroll
    for (int r = 0; r < 4; ++r) {
        int oy = ty0 + 4 * ty + r;
        size_t o = (size_t)n * 65536 + (size_t)oy * 256 + ox;
        #pragma unroll
        for (int j = 0; j < 4; ++j) {
            int q = __float2int_rn(acc[r][j] * FXSCALE);
            atomicAdd(outi + o + j, q);
        }
    }
}

// ---- K8: finalize int fixed-point -> float (in place) -----------------------
__global__ __launch_bounds__(256) void k_fin3(int* __restrict__ o) {
    int i = blockIdx.x * 256 + threadIdx.x;      // 1024 blocks x 256 = 262144
    int4 v = ((const int4*)o)[i];
    float4 f = {v.x * FXINV, v.y * FXINV, v.z * FXINV, v.w * FXINV};
    ((float4*)o)[i] = f;
}

// ---------------------------------------------------------------------------
extern "C" void kernel_launch(void* const* d_in, const int* in_sizes, int n_in,
                              void* d_out, int out_size, void* d_ws, size_t ws_size,
                              hipStream_t stream) {
    const float* x  = (const float*)d_in[0];
    const float* w1 = (const float*)d_in[1];
    const float* g1 = (const float*)d_in[2];
    const float* b1 = (const float*)d_in[3];
    const float* w2 = (const float*)d_in[4];
    const float* g2 = (const float*)d_in[5];
    const float* b2 = (const float*)d_in[6];
    const float* w3 = (const float*)d_in[7];

    WS ws = carve(d_ws);

    k_zero3<<<256, 256, 0, stream>>>((int4*)d_out);
    k_pack_x<<<1024, 256, 0, stream>>>(x, ws.xbits);
    k_pack_w<<<1, 256, 0, stream>>>(w1, w2, ws.wb1, ws.w2lo, ws.w2hi, ws.st1, ws.st2);
    k_stats1<<<512, 256, 0, stream>>>(ws.xbits, ws.wb1, ws.st1);
    k_fin1<<<1, 128, 0, stream>>>(ws.st1, g1, b1, ws.a1, ws.c1);
    k_conv2<<<4096, 256, 0, stream>>>(ws.xbits, ws.wb1, ws.a1, ws.c1,
                                      ws.w2lo, ws.w2hi, ws.h2s);
    k_stats2<<<1024, 256, 0, stream>>>(ws.h2s, ws.st2);
    k_fin2<<<1, 64, 0, stream>>>(ws.st2, g2, b2, ws.a2, ws.c2);
    k_conv3<<<1024, 256, 0, stream>>>(ws.h2s, ws.a2, ws.c2, w3, (int*)d_out);
    k_fin3<<<1024, 256, 0, stream>>>((int*)d_out);
}

// Round 5
// 244.394 us; speedup vs baseline: 2.0227x; 1.1390x over previous
//
#include <hip/hip_runtime.h>
#include <cstdint>
#include <cstddef>
#include <climits>

// ---------------------------------------------------------------------------
// BNN pipeline:
//  L1: conv7x7(sign(x), sign(w1)) -> BN(train) -> leaky(0.5)
//  L2: conv1x1(sign(.), sign(w2)) -> BN(train) -> leaky(0.5)
//  L3: conv5x5 fp32 (64->1)
// Shapes: x (16,1,256,256), out (16,1,256,256)
//
// h2s layout (PADDED in x): int8 [16*64][256][264], col p maps to x = p-2.
//   data at p=2..257; pads p=0,1,258..263 zeroed by k_conv2 edge threads.
//
// conv3: f16 LDS staging + v_dot2_f32_f16 (f32 accum). 2 channel-groups of
// 32ch; partials accumulated into d_out as int32 fixed-point atomics.
// ---------------------------------------------------------------------------

#define NPIX_PER_CH (16.0 * 256.0 * 256.0)
#define PLANE_BYTES 67584      // 256*264
#define ROW_BYTES   264
#define FXSCALE     262144.0f              // 2^18
#define FXINV       3.814697265625e-06f    // 2^-18

typedef _Float16 half2_t __attribute__((ext_vector_type(2)));

#if __has_builtin(__builtin_amdgcn_fdot2)
__device__ __forceinline__ float DOT2(half2_t a, half2_t b, float c) {
    return __builtin_amdgcn_fdot2(a, b, c, false);
}
#else
__device__ __forceinline__ float DOT2(half2_t a, half2_t b, float c) {
    return fmaf((float)a[0], (float)b[0], fmaf((float)a[1], (float)b[1], c));
}
#endif

__device__ __forceinline__ uint32_t pk_f16(float lo, float hi) {
#if __has_builtin(__builtin_amdgcn_cvt_pkrtz)
    auto h = __builtin_amdgcn_cvt_pkrtz(lo, hi);   // __fp16 ext_vector(2)
    return __builtin_bit_cast(uint32_t, h);
#else
    half2_t h; h[0] = (_Float16)lo; h[1] = (_Float16)hi;
    return __builtin_bit_cast(uint32_t, h);
#endif
}
#define H2(u) __builtin_bit_cast(half2_t, (uint32_t)(u))

struct WS {
    int8_t*   h2s;
    uint64_t* xbits;
    uint64_t* wb1;
    uint64_t* w2lo;
    uint64_t* w2hi;
    long long* st1;
    long long* st2;
    int*      K1;                 // [128] integer sign thresholds (layer1)
    unsigned long long* flipm;    // [2]   per-channel flip masks
    float* a2; float* c2;
    uint32_t* wtab;               // [64*32] packed f16 weight pairs for conv3
};

static inline WS carve(void* d_ws) {
    WS w;
    uint8_t* p = (uint8_t*)d_ws;
    w.h2s   = (int8_t*)p;              p += (size_t)16 * 64 * PLANE_BYTES;
    w.xbits = (uint64_t*)p;            p += (size_t)16 * 256 * 6 * 8;
    w.wb1   = (uint64_t*)p;            p += 128 * 8;
    w.w2lo  = (uint64_t*)p;            p += 64 * 8;
    w.w2hi  = (uint64_t*)p;            p += 64 * 8;
    w.st1   = (long long*)p;           p += 256 * 8;
    w.st2   = (long long*)p;           p += 128 * 8;
    w.K1    = (int*)p;                 p += 128 * 4;
    w.flipm = (unsigned long long*)p;  p += 2 * 8;
    w.a2    = (float*)p;               p += 64 * 4;
    w.c2    = (float*)p;               p += 64 * 4;
    w.wtab  = (uint32_t*)p;            p += 64 * 32 * 4;
    return w;
}

// ---- K0: pack sign bits of x into padded per-row words ---------------------
__global__ __launch_bounds__(256) void k_pack_x(const float* __restrict__ x,
                                                uint64_t* __restrict__ xbits) {
    int rowId = blockIdx.x * 4 + (threadIdx.x >> 6);
    int lane  = threadIdx.x & 63;
    const float* row = x + (size_t)rowId * 256;
    uint64_t b0 = __ballot(row[0 * 64 + lane] < 0.0f);
    uint64_t b1 = __ballot(row[1 * 64 + lane] < 0.0f);
    uint64_t b2 = __ballot(row[2 * 64 + lane] < 0.0f);
    uint64_t b3 = __ballot(row[3 * 64 + lane] < 0.0f);
    if (lane == 0) {
        uint64_t* o = xbits + (size_t)rowId * 6;
        o[0] = b0 << 8;
        o[1] = (b0 >> 56) | (b1 << 8);
        o[2] = (b1 >> 56) | (b2 << 8);
        o[3] = (b2 >> 56) | (b3 << 8);
        o[4] = b3 >> 56;
        o[5] = 0;
    }
}

// ---- K1: pack weight sign bits, zero stat accumulators ---------------------
__global__ void k_pack_w(const float* __restrict__ w1, const float* __restrict__ w2,
                         uint64_t* __restrict__ wb1, uint64_t* __restrict__ w2lo,
                         uint64_t* __restrict__ w2hi,
                         long long* __restrict__ st1, long long* __restrict__ st2) {
    int t = threadIdx.x;
    if (t < 128) {
        uint64_t b = 0;
        for (int k = 0; k < 49; ++k)
            if (w1[t * 49 + k] < 0.0f) b |= (1ull << k);
        wb1[t] = b;
    } else if (t < 192) {
        int o = t - 128;
        uint64_t lo = 0, hi = 0;
        for (int c = 0; c < 64; ++c) if (w2[o * 128 + c]      < 0.0f) lo |= (1ull << c);
        for (int c = 0; c < 64; ++c) if (w2[o * 128 + 64 + c] < 0.0f) hi |= (1ull << c);
        w2lo[o] = lo; w2hi[o] = hi;
    }
    st1[t] = 0;
    if (t < 128) st2[t] = 0;
}

// ---- window builder: 49-bit sign window + validity mask --------------------
__device__ inline void build_window(const uint64_t* __restrict__ xb_img, int y, int x,
                                    uint64_t& sbits, uint64_t& vmask) {
    int bitpos = x + 5;
    int w  = bitpos >> 6;
    int sh = bitpos & 63;
    int lo = 3 - x;   if (lo < 0) lo = 0;
    int hi = 258 - x; if (hi > 6) hi = 6;
    uint64_t hm = ((1ull << (hi - lo + 1)) - 1ull) << lo;
    sbits = 0; vmask = 0;
    #pragma unroll
    for (int dy = 0; dy < 7; ++dy) {
        int yy = y - 3 + dy;
        if (yy < 0 || yy > 255) continue;
        const uint64_t* r = xb_img + (size_t)yy * 6;
        uint64_t wA = r[w], wB = r[w + 1];
        uint64_t bits = wA >> sh;
        if (sh) bits |= wB << (64 - sh);
        bits &= 0x7Full;
        sbits |= bits << (7 * dy);
        vmask |= hm   << (7 * dy);
    }
}

// ---- K2: layer-1 BN statistics (exact integer, all-int32 hot loop) ----------
__global__ __launch_bounds__(256) void k_stats1(const uint64_t* __restrict__ xbits,
                                                const uint64_t* __restrict__ wb1g,
                                                long long* __restrict__ st1) {
    __shared__ uint64_t sb[256];
    __shared__ uint64_t vm[256];
    __shared__ int       rs[128];
    __shared__ int       rq[128];
    int t = threadIdx.x;
    int c = t & 127, half = t >> 7;
    uint64_t wb = wb1g[c];
    int sum = 0;
    int sumsq = 0;    // max 1024 px * 49^2 = 2.46M < 2^31
    for (int row = blockIdx.x; row < 4096; row += gridDim.x) {
        int n = row >> 8, y = row & 255;
        const uint64_t* xb_img = xbits + (size_t)n * 256 * 6;
        uint64_t s, v;
        build_window(xb_img, y, t, s, v);
        sb[t] = s; vm[t] = v;
        __syncthreads();
        int base = half << 7;
        #pragma unroll 4
        for (int p = 0; p < 128; ++p) {
            uint64_t ss = sb[base + p], vv = vm[base + p];
            uint64_t d = (ss ^ wb) & vv;
            int h = __popcll(vv) - 2 * __popcll(d);
            sum += h;
            sumsq += h * h;
        }
        __syncthreads();
    }
    if (half == 1) { rs[c] = sum; rq[c] = sumsq; }
    __syncthreads();
    if (half == 0) {
        long long S = (long long)sum + rs[c];
        long long Q = (long long)sumsq + rq[c];
        atomicAdd((unsigned long long*)&st1[c],       (unsigned long long)S);
        atomicAdd((unsigned long long*)&st1[128 + c], (unsigned long long)Q);
    }
}

// ---- K3: BN1 -> integer sign thresholds:  bit = (h < K[c]) ^ flip[c] --------
__global__ void k_fin1(const long long* __restrict__ st1,
                       const float* __restrict__ g1, const float* __restrict__ b1,
                       int* __restrict__ K1, unsigned long long* __restrict__ flipm) {
    int c = threadIdx.x;            // 128 threads (2 waves)
    double mean = (double)st1[c] / NPIX_PER_CH;
    double var  = (double)st1[128 + c] / NPIX_PER_CH - mean * mean;
    double a = (double)g1[c] / sqrt(var + 1e-5);
    double cst = (double)b1[c] - mean * a;
    int K; int flip = 0;
    if (a > 0.0) {
        double v = -cst / a;
        v = fmin(fmax(v, -100.0), 100.0);
        K = (int)ceil(v);                       // bit = h < K
    } else if (a < 0.0) {
        double v = -cst / a;
        v = fmin(fmax(v, -100.0), 100.0);
        K = (int)floor(v) + 1; flip = 1;        // bit = !(h < K)
    } else {
        K = INT_MIN; flip = (cst < 0.0) ? 1 : 0;
    }
    K1[c] = K;
    unsigned long long m = __ballot(flip != 0);
    if ((c & 63) == 0) flipm[c >> 6] = m;
}

// ---- K4: fused conv1(sign) -> BN-sign (int cmp) -> conv2 -> h2/2 ------------
__global__ __launch_bounds__(256) void k_conv2(const uint64_t* __restrict__ xbits,
                                               const uint64_t* __restrict__ wb1g,
                                               const int* __restrict__ K1g,
                                               const unsigned long long* __restrict__ flipm,
                                               const uint64_t* __restrict__ w2log,
                                               const uint64_t* __restrict__ w2hig,
                                               int8_t* __restrict__ h2s) {
    __shared__ uint64_t wb1s[128];
    __shared__ int      K1s[128];
    __shared__ uint64_t w2l[64], w2h[64];
    int t = threadIdx.x;
    if (t < 128) { wb1s[t] = wb1g[t]; K1s[t] = K1g[t]; }
    else if (t < 192) { int o = t - 128; w2l[o] = w2log[o]; w2h[o] = w2hig[o]; }
    __syncthreads();

    int idx = blockIdx.x * 256 + t;
    int n = idx >> 16, rem = idx & 65535;
    int y = rem >> 8, x = rem & 255;
    const uint64_t* xb_img = xbits + (size_t)n * 256 * 6;
    uint64_t sbits, vmask;
    build_window(xb_img, y, x, sbits, vmask);
    int nv = __popcll(vmask);

    uint64_t blo = 0, bhi = 0;
    #pragma unroll 8
    for (int cc = 0; cc < 64; ++cc) {
        uint64_t d = (sbits ^ wb1s[cc]) & vmask;
        int h = nv - 2 * __popcll(d);
        blo |= (uint64_t)(h < K1s[cc]) << cc;
    }
    #pragma unroll 8
    for (int cc = 0; cc < 64; ++cc) {
        uint64_t d = (sbits ^ wb1s[64 + cc]) & vmask;
        int h = nv - 2 * __popcll(d);
        bhi |= (uint64_t)(h < K1s[64 + cc]) << cc;
    }
    blo ^= flipm[0];
    bhi ^= flipm[1];

    size_t base = (size_t)(n * 64) * PLANE_BYTES + (size_t)y * ROW_BYTES;
    #pragma unroll 8
    for (int o = 0; o < 64; ++o) {
        int m = __popcll(blo ^ w2l[o]) + __popcll(bhi ^ w2h[o]);
        h2s[base + (size_t)o * PLANE_BYTES + 2 + x] = (int8_t)(64 - m);
    }
    if (x == 0) {
        #pragma unroll 8
        for (int o = 0; o < 64; ++o)
            *(short*)(h2s + base + (size_t)o * PLANE_BYTES) = 0;
    }
    if (x == 255) {
        #pragma unroll 8
        for (int o = 0; o < 64; ++o) {
            int8_t* r = h2s + base + (size_t)o * PLANE_BYTES;
            *(short*)(r + 258) = 0;
            *(int*)(r + 260) = 0;
        }
    }
}

// ---- K5: layer-2 BN statistics (on stored v = h2/2, padded layout) ----------
__global__ __launch_bounds__(256) void k_stats2(const int8_t* __restrict__ h2s,
                                                long long* __restrict__ st2) {
    int plane = blockIdx.x;       // n*64 + o, 0..1023
    int o = plane & 63;
    int t = threadIdx.x;
    const int4* p = (const int4*)(h2s + (size_t)plane * PLANE_BYTES);
    int sum = 0, sumsq = 0;
    for (int si = t; si < 4224; si += 256) {
        int4 v4 = p[si];
        int wv[4] = {v4.x, v4.y, v4.z, v4.w};
        #pragma unroll
        for (int j = 0; j < 4; ++j) {
            #pragma unroll
            for (int k = 0; k < 4; ++k) {
                int b = (int)(int8_t)((unsigned)wv[j] >> (8 * k));
                sum += b;
                sumsq += b * b;
            }
        }
    }
    for (int off = 32; off; off >>= 1) {
        sum   += __shfl_down(sum, off);
        sumsq += __shfl_down(sumsq, off);
    }
    __shared__ int ws1[4], ws2[4];
    int wid = t >> 6;
    if ((t & 63) == 0) { ws1[wid] = sum; ws2[wid] = sumsq; }
    __syncthreads();
    if (t == 0) {
        long long S = 0, Q = 0;
        for (int i = 0; i < 4; ++i) { S += ws1[i]; Q += ws2[i]; }
        atomicAdd((unsigned long long*)&st2[o],      (unsigned long long)S);
        atomicAdd((unsigned long long*)&st2[64 + o], (unsigned long long)Q);
    }
}

// ---- K6: BN2 coefficients + packed-f16 conv3 weight table -------------------
// wtab[ch*32 + dy*6 + j]: j=0..2 even-x pairs (w0,w1)(w2,w3)(w4,0);
//                         j=3..5 odd-x pairs (0,w0)(w1,w2)(w3,w4)
__global__ void k_fin2(const long long* __restrict__ st2,
                       const float* __restrict__ g2, const float* __restrict__ b2,
                       const float* __restrict__ w3,
                       float* __restrict__ a2, float* __restrict__ c2,
                       uint32_t* __restrict__ wtab) {
    int o = threadIdx.x;            // 64 threads
    double mean = 2.0 * (double)st2[o] / NPIX_PER_CH;
    double msq  = 4.0 * (double)st2[64 + o] / NPIX_PER_CH;
    double var  = msq - mean * mean;
    double inv  = (double)g2[o] / sqrt(var + 1e-5);
    a2[o] = (float)(2.0 * inv);
    c2[o] = (float)((double)b2[o] - mean * inv);

    uint32_t* wp = wtab + o * 32;
    #pragma unroll
    for (int dy = 0; dy < 5; ++dy) {
        float w0 = w3[o * 25 + dy * 5 + 0];
        float w1 = w3[o * 25 + dy * 5 + 1];
        float w2v = w3[o * 25 + dy * 5 + 2];
        float w3v = w3[o * 25 + dy * 5 + 3];
        float w4 = w3[o * 25 + dy * 5 + 4];
        half2_t h;
        h[0] = (_Float16)w0;  h[1] = (_Float16)w1;  wp[dy*6+0] = __builtin_bit_cast(uint32_t, h);
        h[0] = (_Float16)w2v; h[1] = (_Float16)w3v; wp[dy*6+1] = __builtin_bit_cast(uint32_t, h);
        h[0] = (_Float16)w4;  h[1] = (_Float16)0.f; wp[dy*6+2] = __builtin_bit_cast(uint32_t, h);
        h[0] = (_Float16)0.f; h[1] = (_Float16)w0;  wp[dy*6+3] = __builtin_bit_cast(uint32_t, h);
        h[0] = (_Float16)w1;  h[1] = (_Float16)w2v; wp[dy*6+4] = __builtin_bit_cast(uint32_t, h);
        h[0] = (_Float16)w3v; h[1] = (_Float16)w4;  wp[dy*6+5] = __builtin_bit_cast(uint32_t, h);
    }
    wp[30] = 0; wp[31] = 0;
}

// ---- K7a: zero d_out (int accumulator) --------------------------------------
__global__ __launch_bounds__(256) void k_zero3(int4* __restrict__ o) {
    int i = blockIdx.x * 256 + threadIdx.x;
    #pragma unroll
    for (int j = 0; j < 4; ++j)
        o[(size_t)i * 4 + j] = make_int4(0, 0, 0, 0);
}

// ---- K7: conv3 5x5 — f16 LDS + dot2, 2 ch-groups x 32ch, tile 32x64 ---------
// grid: 2 groups x (16 n * 8 yt * 4 xt) = 1024 blocks; 256 threads.
// LDS: 4ch x 36rows x 72cols f16 = 20736 B. Thread: 2y x 4x outputs.
__global__ __launch_bounds__(256, 4) void k_conv3(const int8_t* __restrict__ h2s,
                                                  const float* __restrict__ a2g,
                                                  const float* __restrict__ c2g,
                                                  const uint32_t* __restrict__ wtab,
                                                  int* __restrict__ outi) {
    __shared__ uint16_t lds[4 * 36 * 72];       // f16 bits; ch stride 2592, row 72
    __shared__ float sA2[32], sC2[32];
    int t = threadIdx.x;
    int bid = blockIdx.x;
    int cg   = bid >> 9;                 // 0..1
    int rest = bid & 511;
    int n  = rest >> 5;
    int yt = (rest >> 2) & 7;
    int xt = rest & 3;
    int ty0 = yt * 32, tx0 = xt * 64;
    int cgbase = cg * 32;
    if (t < 32) { sA2[t] = a2g[cgbase + t]; sC2[t] = c2g[cgbase + t]; }

    int ty = t >> 4, tx = t & 15;        // out rows ty0+2ty..+1, cols tx0+4tx..+3
    int n64 = n * 64;

    float acc[2][4] = {{0.f,0.f,0.f,0.f},{0.f,0.f,0.f,0.f}};

    for (int kk = 0; kk < 8; ++kk) {     // 8 chunks x 4 channels
        __syncthreads();                 // first iter also guards sA2/sC2
        // stage 4ch x 36rows x 17 int-quads = 2448 items -> f16 pairs
        for (int si = t; si < 2448; si += 256) {
            int cl  = si / 612;
            int rem = si - cl * 612;
            int row = rem / 17;
            int q   = rem - row * 17;
            int gy  = ty0 - 2 + row;
            int lc  = 4 * kk + cl;
            float a = sA2[lc], c = sC2[lc];
            uint32_t u0 = 0, u1 = 0;
            if ((unsigned)gy < 256u) {
                int v = *(const int*)(h2s + (size_t)(n64 + cgbase + lc) * PLANE_BYTES
                                          + (size_t)gy * ROW_BYTES + tx0 + q * 4);
                float z0 = fmaf(a, (float)(int)(int8_t)(v),        c);
                float z1 = fmaf(a, (float)(int)(int8_t)(v >> 8),   c);
                float z2 = fmaf(a, (float)(int)(int8_t)(v >> 16),  c);
                float z3 = fmaf(a, (float)(int)(int8_t)(v >> 24),  c);
                z0 = fmaxf(z0, 0.5f * z0);
                z1 = fmaxf(z1, 0.5f * z1);
                z2 = fmaxf(z2, 0.5f * z2);
                z3 = fmaxf(z3, 0.5f * z3);
                u0 = pk_f16(z0, z1);
                u1 = pk_f16(z2, z3);
            }
            uint2 wv = {u0, u1};
            *(uint2*)(lds + cl * 2592 + row * 72 + q * 4) = wv;
        }
        __syncthreads();

        #pragma unroll
        for (int cl = 0; cl < 4; ++cl) {
            const uint32_t* wp = wtab + (size_t)(cgbase + 4 * kk + cl) * 32; // uniform
            const uint16_t* base = lds + cl * 2592 + (2 * ty) * 72 + 4 * tx;
            #pragma unroll
            for (int rr = 0; rr < 6; ++rr) {
                uint2 A = *(const uint2*)(base + rr * 72);
                uint2 B = *(const uint2*)(base + rr * 72 + 4);
                half2_t W0 = H2(A.x), W1 = H2(A.y), W2 = H2(B.x), W3 = H2(B.y);
                #pragma unroll
                for (int dyp = rr - 1; dyp <= rr; ++dyp) {
                    if (dyp < 0 || dyp > 4) continue;       // compile-time
                    int r = rr - dyp;                       // 0 or 1
                    const uint32_t* wd = wp + dyp * 6;
                    acc[r][0] = DOT2(W0, H2(wd[0]), DOT2(W1, H2(wd[1]), DOT2(W2, H2(wd[2]), acc[r][0])));
                    acc[r][1] = DOT2(W0, H2(wd[3]), DOT2(W1, H2(wd[4]), DOT2(W2, H2(wd[5]), acc[r][1])));
                    acc[r][2] = DOT2(W1, H2(wd[0]), DOT2(W2, H2(wd[1]), DOT2(W3, H2(wd[2]), acc[r][2])));
                    acc[r][3] = DOT2(W1, H2(wd[3]), DOT2(W2, H2(wd[4]), DOT2(W3, H2(wd[5]), acc[r][3])));
                }
            }
        }
    }

    int ox = tx0 + 4 * tx;
    #pragma unroll
    for (int r = 0; r < 2; ++r) {
        int oy = ty0 + 2 * ty + r;
        size_t o = (size_t)n * 65536 + (size_t)oy * 256 + ox;
        #pragma unroll
        for (int j = 0; j < 4; ++j) {
            int q = __float2int_rn(acc[r][j] * FXSCALE);
            atomicAdd(outi + o + j, q);
        }
    }
}

// ---- K8: finalize int fixed-point -> float (in place) -----------------------
__global__ __launch_bounds__(256) void k_fin3(int* __restrict__ o) {
    int i = blockIdx.x * 256 + threadIdx.x;
    int4 v = ((const int4*)o)[i];
    float4 f = {v.x * FXINV, v.y * FXINV, v.z * FXINV, v.w * FXINV};
    ((float4*)o)[i] = f;
}

// ---------------------------------------------------------------------------
extern "C" void kernel_launch(void* const* d_in, const int* in_sizes, int n_in,
                              void* d_out, int out_size, void* d_ws, size_t ws_size,
                              hipStream_t stream) {
    const float* x  = (const float*)d_in[0];
    const float* w1 = (const float*)d_in[1];
    const float* g1 = (const float*)d_in[2];
    const float* b1 = (const float*)d_in[3];
    const float* w2 = (const float*)d_in[4];
    const float* g2 = (const float*)d_in[5];
    const float* b2 = (const float*)d_in[6];
    const float* w3 = (const float*)d_in[7];

    WS ws = carve(d_ws);

    k_zero3<<<256, 256, 0, stream>>>((int4*)d_out);
    k_pack_x<<<1024, 256, 0, stream>>>(x, ws.xbits);
    k_pack_w<<<1, 256, 0, stream>>>(w1, w2, ws.wb1, ws.w2lo, ws.w2hi, ws.st1, ws.st2);
    k_stats1<<<1024, 256, 0, stream>>>(ws.xbits, ws.wb1, ws.st1);
    k_fin1<<<1, 128, 0, stream>>>(ws.st1, g1, b1, ws.K1, ws.flipm);
    k_conv2<<<4096, 256, 0, stream>>>(ws.xbits, ws.wb1, ws.K1, ws.flipm,
                                      ws.w2lo, ws.w2hi, ws.h2s);
    k_stats2<<<1024, 256, 0, stream>>>(ws.h2s, ws.st2);
    k_fin2<<<1, 64, 0, stream>>>(ws.st2, g2, b2, w3, ws.a2, ws.c2, ws.wtab);
    k_conv3<<<1024, 256, 0, stream>>>(ws.h2s, ws.a2, ws.c2, ws.wtab, (int*)d_out);
    k_fin3<<<1024, 256, 0, stream>>>((int*)d_out);
}